// Round 1
// 466.389 us; speedup vs baseline: 1.0807x; 1.0807x over previous
//
#include <hip/hip_runtime.h>
#include <cstdint>
#include <cstddef>

#define LA 4096
#define LB 4096
#define DD 1024

typedef unsigned short u16;
typedef short bf16x8 __attribute__((ext_vector_type(8)));
typedef float f32x4 __attribute__((ext_vector_type(4)));

__device__ __forceinline__ u16 f2bf(float f) {
  unsigned u = __builtin_bit_cast(unsigned, f);
  u += 0x7fffu + ((u >> 16) & 1u);
  return (u16)(u >> 16);
}
__device__ __forceinline__ float bf2f(u16 h) {
  return __builtin_bit_cast(float, (unsigned)h << 16);
}
__device__ __forceinline__ bf16x8 pack8(float4 a, float4 b) {
  bf16x8 r;
  r[0] = (short)f2bf(a.x); r[1] = (short)f2bf(a.y);
  r[2] = (short)f2bf(a.z); r[3] = (short)f2bf(a.w);
  r[4] = (short)f2bf(b.x); r[5] = (short)f2bf(b.y);
  r[6] = (short)f2bf(b.z); r[7] = (short)f2bf(b.w);
  return r;
}
// async global->LDS, 16B/lane; lds base must be wave-uniform (HW adds lane*16)
__device__ __forceinline__ void async16(const void* g, void* l) {
  __builtin_amdgcn_global_load_lds(
      (const __attribute__((address_space(1))) unsigned int*)g,
      (__attribute__((address_space(3))) unsigned int*)l, 16, 0, 0);
}

// ---- prepass: split fp32 X -> Xhi + Xlo (bf16 residual pair) ---------------
__global__ __launch_bounds__(256) void split_ab(const float* __restrict__ A,
                                                const float* __restrict__ B,
                                                u16* __restrict__ Ahi, u16* __restrict__ Alo,
                                                u16* __restrict__ Bhi, u16* __restrict__ Blo) {
  const int side = blockIdx.x >> 11;
  const size_t idx = ((size_t)(blockIdx.x & 2047) * 256 + threadIdx.x) * 8;
  const float* src = side ? B : A;
  u16* dh = side ? Bhi : Ahi;
  u16* dl = side ? Blo : Alo;
  const float4 a = *(const float4*)&src[idx];
  const float4 b = *(const float4*)&src[idx + 4];
  float v[8] = {a.x, a.y, a.z, a.w, b.x, b.y, b.z, b.w};
  bf16x8 hi, lo;
#pragma unroll
  for (int i = 0; i < 8; ++i) {
    const u16 h = f2bf(v[i]);
    hi[i] = (short)h;
    lo[i] = (short)f2bf(v[i] - bf2f(h));
  }
  *(bf16x8*)&dh[idx] = hi;
  *(bf16x8*)&dl[idx] = lo;
}

// ------- tiled transpose fp32 -> bf16: out[c][r] = bf16(in[r][c]) -----------
__global__ __launch_bounds__(256) void tr_f32(const float* __restrict__ in,
                                              u16* __restrict__ out,
                                              int R, int C) {
  __shared__ u16 t[32][33];
  const int c0 = blockIdx.x * 32, r0 = blockIdx.y * 32;
  const int tid = threadIdx.x;
  const int lr = tid >> 3, lc = (tid & 7) * 4;
  const float4 v = *(const float4*)&in[(size_t)(r0 + lr) * C + c0 + lc];
  t[lr][lc + 0] = f2bf(v.x); t[lr][lc + 1] = f2bf(v.y);
  t[lr][lc + 2] = f2bf(v.z); t[lr][lc + 3] = f2bf(v.w);
  __syncthreads();
  ushort4 w;
  w.x = t[lc + 0][lr]; w.y = t[lc + 1][lr]; w.z = t[lc + 2][lr]; w.w = t[lc + 3][lr];
  *(ushort4*)&out[(size_t)(c0 + lr) * R + r0 + lc] = w;
}

// ------- energy = A @ B^T, split-bf16 3-term, ASYNC staging (m97-style) -----
__global__ __launch_bounds__(256) void gemm_energy(const u16* __restrict__ Ahi,
                                                   const u16* __restrict__ Alo,
                                                   const u16* __restrict__ Bhi,
                                                   const u16* __restrict__ Blo,
                                                   float* __restrict__ E) {
  __shared__ u16 lah[128 * 32], lal[128 * 32], lbh[128 * 32], lbl[128 * 32];
  const int j0 = blockIdx.x * 128;
  const int i0 = blockIdx.y * 128;
  const int tid = threadIdx.x;
  const int lane = tid & 63, quad = lane >> 4, lq = lane & 15;
  const int wave = tid >> 6;
  const int wm = (wave & 1) * 64, wn = (wave >> 1) * 64;
  f32x4 acc[4][4] = {};
  for (int kt = 0; kt < DD; kt += 32) {
    if (kt) __syncthreads();
#pragma unroll
    for (int r = 0; r < 2; ++r) {
      const int chunk = wave * 128 + r * 64 + lane;
      const int row = chunk >> 2;
      const int kc = (chunk & 3) * 8;
      const int lofs = (wave * 128 + r * 64) * 16;
      const size_t ga = (size_t)(i0 + row) * DD + kt + kc;
      const size_t gb = (size_t)(j0 + row) * DD + kt + kc;
      async16(Ahi + ga, (char*)lah + lofs);
      async16(Alo + ga, (char*)lal + lofs);
      async16(Bhi + gb, (char*)lbh + lofs);
      async16(Blo + gb, (char*)lbl + lofs);
    }
    __syncthreads();
    bf16x8 fah[4], fal[4], fbh[4], fbl[4];
#pragma unroll
    for (int f = 0; f < 4; ++f) {
      fah[f] = *(const bf16x8*)&lah[(wm + f * 16 + lq) * 32 + quad * 8];
      fal[f] = *(const bf16x8*)&lal[(wm + f * 16 + lq) * 32 + quad * 8];
      fbh[f] = *(const bf16x8*)&lbh[(wn + f * 16 + lq) * 32 + quad * 8];
      fbl[f] = *(const bf16x8*)&lbl[(wn + f * 16 + lq) * 32 + quad * 8];
    }
#pragma unroll
    for (int fm = 0; fm < 4; ++fm)
#pragma unroll
      for (int fn = 0; fn < 4; ++fn) {
        acc[fm][fn] = __builtin_amdgcn_mfma_f32_16x16x32_bf16(fal[fm], fbh[fn], acc[fm][fn], 0, 0, 0);
        acc[fm][fn] = __builtin_amdgcn_mfma_f32_16x16x32_bf16(fah[fm], fbl[fn], acc[fm][fn], 0, 0, 0);
        acc[fm][fn] = __builtin_amdgcn_mfma_f32_16x16x32_bf16(fah[fm], fbh[fn], acc[fm][fn], 0, 0, 0);
      }
  }
#pragma unroll
  for (int fm = 0; fm < 4; ++fm)
#pragma unroll
    for (int fn = 0; fn < 4; ++fn)
#pragma unroll
      for (int r = 0; r < 4; ++r) {
        const int gi = i0 + wm + fm * 16 + quad * 4 + r;
        const int gj = j0 + wn + fn * 16 + lq;
        E[(size_t)gi * LB + gj] = acc[fm][fn][r];
      }
}

// ---- fused: row softmax stats + Pa[i][j]=bf16(exp(E-rmax)) + zero wave_a ---
// One block per row; whole row lives in registers, E is read ONCE.
__global__ __launch_bounds__(256) void row_softmax_pa(const float* __restrict__ E,
                                                      float* __restrict__ rinv,
                                                      u16* __restrict__ P,
                                                      float* __restrict__ wa) {
  __shared__ float red[8];
  const int row = blockIdx.x, tid = threadIdx.x;
  const float* e = E + (size_t)row * LB;
  float4 v[4];
#pragma unroll
  for (int c = 0; c < 4; ++c) v[c] = *(const float4*)&e[(c * 256 + tid) * 4];
  float m = -__builtin_inff();
#pragma unroll
  for (int c = 0; c < 4; ++c)
    m = fmaxf(m, fmaxf(fmaxf(v[c].x, v[c].y), fmaxf(v[c].z, v[c].w)));
#pragma unroll
  for (int o = 32; o > 0; o >>= 1) m = fmaxf(m, __shfl_down(m, o));
  if ((tid & 63) == 0) red[tid >> 6] = m;
  __syncthreads();
  m = fmaxf(fmaxf(red[0], red[1]), fmaxf(red[2], red[3]));
  float s = 0.f;
#pragma unroll
  for (int c = 0; c < 4; ++c)
    s += __expf(v[c].x - m) + __expf(v[c].y - m) + __expf(v[c].z - m) + __expf(v[c].w - m);
#pragma unroll
  for (int o = 32; o > 0; o >>= 1) s += __shfl_down(s, o);
  if ((tid & 63) == 0) red[4 + (tid >> 6)] = s;
  __syncthreads();
  if (tid == 0) rinv[row] = 1.f / (red[4] + red[5] + red[6] + red[7]);
  // write Pa row (unnormalized exp, bf16) -- same bits as old make_pa
#pragma unroll
  for (int c = 0; c < 4; ++c) {
    ushort4 w;
    w.x = f2bf(__expf(v[c].x - m));
    w.y = f2bf(__expf(v[c].y - m));
    w.z = f2bf(__expf(v[c].z - m));
    w.w = f2bf(__expf(v[c].w - m));
    *(ushort4*)&P[(size_t)row * LB + (c * 256 + tid) * 4] = w;
  }
  // zero-init wave_a row for split-K atomic accumulation
  float4 z = {0.f, 0.f, 0.f, 0.f};
  *(float4*)&wa[(size_t)row * DD + tid * 4] = z;
}

// ---------------- column softmax stats --------------------------------------
__global__ __launch_bounds__(256) void col_partial(const float* __restrict__ E,
                                                   float* __restrict__ pmax,
                                                   float* __restrict__ psum) {
  const int c = blockIdx.x * 256 + threadIdx.x;
  const int rg = blockIdx.y;
  const float* e = E + (size_t)rg * 128 * LB + c;
  float m = -__builtin_inff(), s = 0.f;
#pragma unroll 4
  for (int r = 0; r < 128; ++r) {
    const float x = e[(size_t)r * LB];
    const float nm = fmaxf(m, x);
    s = s * __expf(m - nm) + __expf(x - nm);
    m = nm;
  }
  pmax[rg * LB + c] = m;
  psum[rg * LB + c] = s;
}

__global__ __launch_bounds__(256) void col_combine(const float* __restrict__ pmax,
                                                   const float* __restrict__ psum,
                                                   float* __restrict__ cmax,
                                                   float* __restrict__ cinv) {
  const int c = blockIdx.x * 256 + threadIdx.x;
  float m = -__builtin_inff(), s = 0.f;
#pragma unroll 4
  for (int g = 0; g < 32; ++g) {
    const float pm = pmax[g * LB + c], ps = psum[g * LB + c];
    const float nm = fmaxf(m, pm);
    s = s * __expf(m - nm) + ps * __expf(pm - nm);
    m = nm;
  }
  cmax[c] = m;
  cinv[c] = 1.f / s;
}

// ---- Pb[j][i] = bf16(exp(E[i][j] - cmax[j])), transposing ------------------
__global__ __launch_bounds__(256) void make_pb(const float* __restrict__ E,
                                               const float* __restrict__ cmax,
                                               u16* __restrict__ P) {
  __shared__ u16 t[32][33];
  const int j0 = blockIdx.x * 32;
  const int i0 = blockIdx.y * 32;
  const int tid = threadIdx.x;
  const int lr = tid >> 3, lc = (tid & 7) * 4;
  const float4 v = *(const float4*)&E[(size_t)(i0 + lr) * LB + j0 + lc];
  const float4 cm = *(const float4*)&cmax[j0 + lc];
  t[lr][lc + 0] = f2bf(__expf(v.x - cm.x));
  t[lr][lc + 1] = f2bf(__expf(v.y - cm.y));
  t[lr][lc + 2] = f2bf(__expf(v.z - cm.z));
  t[lr][lc + 3] = f2bf(__expf(v.w - cm.w));
  __syncthreads();
  ushort4 w;
  w.x = t[lc + 0][lr]; w.y = t[lc + 1][lr]; w.z = t[lc + 2][lr]; w.w = t[lc + 3][lr];
  *(ushort4*)&P[(size_t)(j0 + lr) * LA + i0 + lc] = w;
}

// ---- W[i][d] = inv[i] * sum_j P[i][j] Vt[d][j], split-K x2 -----------------
// ATOMIC=1: both K-halves unsafeAtomicAdd into pre-zeroed W0 (scale is linear
//           so inv applies per-partial). ATOMIC=0: kz=0 -> W0, kz=1 -> W1
//           (plain stores; consumer sums the two partials).
template <int ATOMIC>
__global__ __launch_bounds__(256) void gemm_pv(const u16* __restrict__ P,
                                               const u16* __restrict__ Vt,
                                               const float* __restrict__ inv,
                                               float* __restrict__ W0,
                                               float* __restrict__ W1) {
  __shared__ u16 lds_a[128 * 32];
  __shared__ u16 lds_b[128 * 32];
  const int n0 = blockIdx.x * 128;
  const int i0 = blockIdx.y * 128;
  const int kz = blockIdx.z;
  const int tid = threadIdx.x;
  const int lane = tid & 63, quad = lane >> 4, lq = lane & 15;
  const int wave = tid >> 6;
  const int wm = (wave & 1) * 64, wn = (wave >> 1) * 64;
  f32x4 acc[4][4] = {};
  for (int t = 0; t < 64; ++t) {
    const int kt = kz * 2048 + t * 32;
    if (t) __syncthreads();
#pragma unroll
    for (int r = 0; r < 2; ++r) {
      const int chunk = wave * 128 + r * 64 + lane;
      const int row = chunk >> 2;
      const int kc = (chunk & 3) * 8;
      const int lofs = (wave * 128 + r * 64) * 16;
      async16(P + (size_t)(i0 + row) * 4096 + kt + kc, (char*)lds_a + lofs);
      async16(Vt + (size_t)(n0 + row) * 4096 + kt + kc, (char*)lds_b + lofs);
    }
    __syncthreads();
    bf16x8 af[4], bfr[4];
#pragma unroll
    for (int f = 0; f < 4; ++f) {
      af[f]  = *(const bf16x8*)&lds_a[(wm + f * 16 + lq) * 32 + quad * 8];
      bfr[f] = *(const bf16x8*)&lds_b[(wn + f * 16 + lq) * 32 + quad * 8];
    }
#pragma unroll
    for (int fm = 0; fm < 4; ++fm)
#pragma unroll
      for (int fn = 0; fn < 4; ++fn)
        acc[fm][fn] = __builtin_amdgcn_mfma_f32_16x16x32_bf16(af[fm], bfr[fn], acc[fm][fn], 0, 0, 0);
  }
  float* W = ATOMIC ? W0 : (kz ? W1 : W0);
#pragma unroll
  for (int fm = 0; fm < 4; ++fm)
#pragma unroll
    for (int r = 0; r < 4; ++r) {
      const int gm = i0 + wm + fm * 16 + quad * 4 + r;
      const float sc = inv[gm];
#pragma unroll
      for (int fn = 0; fn < 4; ++fn) {
        const int gn = n0 + wn + fn * 16 + lq;
        if (ATOMIC)
          unsafeAtomicAdd(&W[(size_t)gm * DD + gn], acc[fm][fn][r] * sc);
        else
          W[(size_t)gm * DD + gn] = acc[fm][fn][r] * sc;
      }
    }
}

// ---------------- elementwise finish (FP32 out): copy / w / a-w / a*w -------
// side b: wave = partial0 (in ob[S..2S)) + partial1 (p1); summed wave written
// back to ob[S..2S). p1 aliases ob[2S..3S) with perfect same-thread overlap.
__global__ __launch_bounds__(256) void finish(const float* __restrict__ Ain,
                                              const float* __restrict__ Bin,
                                              const float* __restrict__ p1,
                                              float* __restrict__ out) {
  const int side = blockIdx.x >> 11;
  const int blk = blockIdx.x & 2047;
  const size_t idx = ((size_t)blk * 256 + threadIdx.x) * 8;
  const size_t S = (size_t)LA * DD;
  const float* src = side ? Bin : Ain;
  float* ob = out + (size_t)side * 4 * S;
  const float4 a0 = *(const float4*)&src[idx];
  const float4 a1 = *(const float4*)&src[idx + 4];
  float4 w0 = *(const float4*)&ob[S + idx];
  float4 w1 = *(const float4*)&ob[S + idx + 4];
  if (side) {
    const float4 q0 = *(const float4*)&p1[idx];
    const float4 q1 = *(const float4*)&p1[idx + 4];
    w0.x += q0.x; w0.y += q0.y; w0.z += q0.z; w0.w += q0.w;
    w1.x += q1.x; w1.y += q1.y; w1.z += q1.z; w1.w += q1.w;
    *(float4*)&ob[S + idx] = w0;
    *(float4*)&ob[S + idx + 4] = w1;
  }
  float4 s0, s1, m0, m1;
  s0.x = a0.x - w0.x; s0.y = a0.y - w0.y; s0.z = a0.z - w0.z; s0.w = a0.w - w0.w;
  s1.x = a1.x - w1.x; s1.y = a1.y - w1.y; s1.z = a1.z - w1.z; s1.w = a1.w - w1.w;
  m0.x = a0.x * w0.x; m0.y = a0.y * w0.y; m0.z = a0.z * w0.z; m0.w = a0.w * w0.w;
  m1.x = a1.x * w1.x; m1.y = a1.y * w1.y; m1.z = a1.z * w1.z; m1.w = a1.w * w1.w;
  *(float4*)&ob[idx] = a0;            *(float4*)&ob[idx + 4] = a1;
  *(float4*)&ob[2 * S + idx] = s0;    *(float4*)&ob[2 * S + idx + 4] = s1;
  *(float4*)&ob[3 * S + idx] = m0;    *(float4*)&ob[3 * S + idx + 4] = m1;
}

extern "C" void kernel_launch(void* const* d_in, const int* in_sizes, int n_in,
                              void* d_out, int out_size, void* d_ws, size_t ws_size,
                              hipStream_t stream) {
  const float* A = (const float*)d_in[0];
  const float* B = (const float*)d_in[1];
  float* out = (float*)d_out;          // FP32 output: 8 slots of S floats
  const size_t S = (size_t)LA * DD;    // 4,194,304

  // d_ws UNUSED. Scratch choreography inside the 128 MiB fp32 out buffer:
  //   slot0: stats (1.1MB) + Bt (u16 at float-ofs 1M) ; finish side0 copy LAST
  //   slot1: wave_a (zeroed by row_softmax_pa, atomically accumulated)
  //   slots2-3: Ahi/Alo/Bhi/Blo (4x8MB) -> then Pa, then Pb (32MB)
  //   slots4-7: E (64MB) -> then At (slot4), wave_b p0 (slot5), p1 (slot6)
  float* pmax = out;                       // 131072
  float* psum = pmax + 131072;             // 131072
  float* rmax = psum + 131072;             // 4096 (unused slot kept for layout)
  float* rinv = rmax + 4096;
  float* cmax = rinv + 4096;
  float* cinv = cmax + 4096;
  u16*   Bt   = (u16*)(out + 1048576);     // [DD][LB] u16, 8MB
  u16*   Ahi  = (u16*)(out + 2 * S);       // 8MB each
  u16*   Alo  = Ahi + S;
  u16*   Bhi  = Alo + S;
  u16*   Blo  = Bhi + S;
  u16*   P    = (u16*)(out + 2 * S);       // [4096][4096] u16 (after hi/lo dead)
  float* E    = out + 4 * S;               // [4096][4096] fp32, 64MB
  u16*   At   = (u16*)(out + 4 * S);       // [DD][LA] u16 (after E consumed)
  float* wave_a = out + S;
  float* wave_b = out + 5 * S;             // side-b partial 0
  float* pB1    = out + 6 * S;             // side-b partial 1

  split_ab<<<dim3(4096), 256, 0, stream>>>(A, B, Ahi, Alo, Bhi, Blo);
  gemm_energy<<<dim3(LB / 128, LA / 128), 256, 0, stream>>>(Ahi, Alo, Bhi, Blo, E);

  // row softmax + Pa in ONE E pass; also zeroes wave_a for the atomic PV
  row_softmax_pa<<<dim3(LA), 256, 0, stream>>>(E, rinv, P, wave_a);
  col_partial<<<dim3(LB / 256, 32), 256, 0, stream>>>(E, pmax, psum);
  col_combine<<<dim3(LB / 256), 256, 0, stream>>>(pmax, psum, cmax, cinv);

  // wave_a: split-K x2 (512 blocks -> 2 blocks/CU), atomic combine
  tr_f32<<<dim3(DD / 32, LB / 32), 256, 0, stream>>>(B, Bt, LB, DD);
  gemm_pv<1><<<dim3(DD / 128, LA / 128, 2), 256, 0, stream>>>(P, Bt, rinv, wave_a, nullptr);

  // wave_b: split-K x2, two plain partials (slot5 + slot6), summed in finish
  make_pb<<<dim3(LB / 32, LA / 32), 256, 0, stream>>>(E, cmax, P);
  tr_f32<<<dim3(DD / 32, LA / 32), 256, 0, stream>>>(A, At, LA, DD);
  gemm_pv<0><<<dim3(DD / 128, LB / 128, 2), 256, 0, stream>>>(P, At, cinv, wave_b, pB1);

  finish<<<dim3(4096), 256, 0, stream>>>(A, B, pB1, out);
}